// Round 1
// baseline (591.044 us; speedup 1.0000x reference)
//
#include <hip/hip_runtime.h>

#define BATCH 32
#define SEQL 4096
#define DIM 768
#define D4 192           // DIM / 4 (one float4 of D per lane-slot)
#define WIN 32
#define NPOS 65          // 2*WIN + 1
#define GROUPS 5
#define PERGRP 13        // GROUPS * PERGRP == NPOS
#define BLK (GROUPS * D4) // 960 threads = 15 waves
#define LN_EPS 1e-5f

// Single fused kernel: windowed (alt-ref) masked mean + LayerNorm over D.
// grid = BATCH, block = 960 (5 position-groups x 192 lanes).
// No workspace usage at all — tests the theory that the 1.5 GiB harness
// poison fill of d_ws is what dominates the timed window.
__global__ __launch_bounds__(BLK) void fused_pool_ln_kernel(
    const float4* __restrict__ refv, const float4* __restrict__ altv,
    const int* __restrict__ pos,
    const float4* __restrict__ gammav, const float4* __restrict__ betav,
    float4* __restrict__ outv) {
  const int b   = blockIdx.x;
  const int tid = threadIdx.x;
  const int g   = tid / D4;   // position group 0..4 (3-wave aligned)
  const int t   = tid % D4;   // float4 lane within D

  const int p  = pos[b];
  const int p0 = p - WIN + g * PERGRP;

  // Phase 1: each group sums its 13 window rows of (alt - ref).
  float4 acc = make_float4(0.f, 0.f, 0.f, 0.f);
#pragma unroll
  for (int i = 0; i < PERGRP; ++i) {
    const int q = p0 + i;            // wave-uniform predicate (g,i uniform per wave)
    if (q >= 0 && q < SEQL) {
      const size_t off = ((size_t)b * SEQL + q) * D4 + t;
      const float4 a = altv[off];
      const float4 r = refv[off];
      acc.x += a.x - r.x;
      acc.y += a.y - r.y;
      acc.z += a.z - r.z;
      acc.w += a.w - r.w;
    }
  }

  __shared__ float4 sh[BLK];       // 15360 B
  __shared__ float  sh2[6];
  sh[tid] = acc;
  __syncthreads();

  // Phase 2: first 3 waves combine the 5 group partials and do LayerNorm.
  float4 s = make_float4(0.f, 0.f, 0.f, 0.f);
  if (tid < D4) {
    s = sh[t];
#pragma unroll
    for (int gg = 1; gg < GROUPS; ++gg) {
      const float4 v = sh[gg * D4 + t];
      s.x += v.x; s.y += v.y; s.z += v.z; s.w += v.w;
    }
    const int lo = (p - WIN) > 0 ? (p - WIN) : 0;
    const int hi = (p + WIN) < (SEQL - 1) ? (p + WIN) : (SEQL - 1);
    const float inv_cnt = 1.f / (float)(hi - lo + 1);
    s.x *= inv_cnt; s.y *= inv_cnt; s.z *= inv_cnt; s.w *= inv_cnt;

    float lsum = s.x + s.y + s.z + s.w;
    float lsq  = s.x * s.x + s.y * s.y + s.z * s.z + s.w * s.w;
#pragma unroll
    for (int off = 32; off > 0; off >>= 1) {
      lsum += __shfl_down(lsum, off);
      lsq  += __shfl_down(lsq, off);
    }
    const int wave = tid >> 6;
    if ((tid & 63) == 0) {
      sh2[wave]     = lsum;
      sh2[3 + wave] = lsq;
    }
  }
  __syncthreads();   // all 960 threads reach this

  if (tid < D4) {
    const float tot   = sh2[0] + sh2[1] + sh2[2];
    const float totsq = sh2[3] + sh2[4] + sh2[5];
    const float mu   = tot * (1.f / (float)DIM);
    const float var  = totsq * (1.f / (float)DIM) - mu * mu;
    const float rstd = rsqrtf(var + LN_EPS);

    const float4 gm = gammav[t];
    const float4 bt = betav[t];
    float4 o;
    o.x = (s.x - mu) * rstd * gm.x + bt.x;
    o.y = (s.y - mu) * rstd * gm.y + bt.y;
    o.z = (s.z - mu) * rstd * gm.z + bt.z;
    o.w = (s.w - mu) * rstd * gm.w + bt.w;
    outv[(size_t)b * D4 + t] = o;
  }
}

extern "C" void kernel_launch(void* const* d_in, const int* in_sizes, int n_in,
                              void* d_out, int out_size, void* d_ws, size_t ws_size,
                              hipStream_t stream) {
  const float* ref_repr = (const float*)d_in[0];
  const float* alt_repr = (const float*)d_in[1];
  const int*   vpos     = (const int*)d_in[2];
  const float* gamma    = (const float*)d_in[3];
  const float* beta     = (const float*)d_in[4];
  float* out = (float*)d_out;
  (void)d_ws; (void)ws_size;   // intentionally unused — no workspace

  fused_pool_ln_kernel<<<BATCH, BLK, 0, stream>>>(
      (const float4*)ref_repr, (const float4*)alt_repr, vpos,
      (const float4*)gamma, (const float4*)beta, (float4*)out);
}